// Round 8
// baseline (303.307 us; speedup 1.0000x reference)
//
#include <hip/hip_runtime.h>

using u16 = unsigned short;
using u32 = unsigned int;

typedef __bf16 bf16x8 __attribute__((ext_vector_type(8)));
typedef float  f32x4  __attribute__((ext_vector_type(4)));

__device__ __forceinline__ u16 f2bf(float f) {
    u32 u = __float_as_uint(f);
    u32 r = u + 0x7fffu + ((u >> 16) & 1u);
    return (u16)(r >> 16);
}
__device__ __forceinline__ float gelu_f(float x) {
    return 0.5f * x * (1.0f + erff(x * 0.70710678118654752440f));
}

// ---------------- prep: cvt W1/W2 to plain bf16 [f][k] ----------------
__global__ __launch_bounds__(256) void prep_kernel(
    const float* __restrict__ W1, const float* __restrict__ W2,
    u16* __restrict__ W1b, u16* __restrict__ W2b)
{
    int i = blockIdx.x * 256 + threadIdx.x;          // 0..131071
    const float* src = (i < 65536) ? W1 : W2;
    u16* dst = (i < 65536) ? W1b : W2b;
    int ii = i & 65535;
    float4 v = ((const float4*)src)[ii];
    ushort4 o;
    o.x = f2bf(v.x); o.y = f2bf(v.y); o.z = f2bf(v.z); o.w = f2bf(v.w);
    ((ushort4*)dst)[ii] = o;
}

// ---------------- mega: full 2-layer GAT per graph, 1 block/graph, 8 waves ----------------
// LDS: Hs 128KB (x-bf16 -> H1^T -> H1' -> H2^T), SG 16KB:
//   [0,8K) cnt u4[128][128] packed in u32[128][16]
//   [8K,10K) stats f32[512]: ss[128] sd[128] M[128] rD[128]
// W operand comes from per-lane global loads (L2-resident) into a depth-4 register ring.
__global__ __launch_bounds__(512, 1) void mega_kernel(
    const float* __restrict__ x, const int* __restrict__ ei, const int* __restrict__ valid,
    const u16* __restrict__ W1b, const float* __restrict__ a1s, const float* __restrict__ a1d,
    const float* __restrict__ b1,
    const u16* __restrict__ W2b, const float* __restrict__ a2s, const float* __restrict__ a2d,
    const float* __restrict__ b2,
    float* __restrict__ outF)
{
    __shared__ u16 Hs[65536];
    __shared__ __align__(16) u16 SG[8192];
    u32*   cntw = (u32*)SG;                 // [0, 8K) bytes
    float* stf  = (float*)(SG + 4096);      // [8K, 10K) bytes

    const int tid  = threadIdx.x;
    const int lane = tid & 63;
    const int w    = tid >> 6;
    const int rl   = lane & 15;
    const int grp  = lane >> 4;
    const int gid  = blockIdx.x;
    const int bb   = gid >> 5, tt = gid & 31;

    // ---- phase 0: edge prefetch, cnt/stats zero, x -> bf16 Hs (swizzled) ----
    const int4* es = (const int4*)(ei + (size_t)gid * 4096);
    int4 e0 = es[tid], e1 = es[512 + tid];

    for (int i = tid; i < 2048; i += 512) cntw[i] = 0u;
    stf[tid] = 0.f;

    const float4* xg = (const float4*)(x + (size_t)gid * 65536);
    #pragma unroll
    for (int it = 0; it < 16; ++it) {
        float4 a = xg[tid * 2 + it * 1024];
        float4 b = xg[tid * 2 + 1 + it * 1024];
        int m = it * 8 + w;
        int sp = lane ^ ((lane >> 3) & 7) ^ (m & 7);
        ushort4 lo, hi;
        lo.x = f2bf(a.x); lo.y = f2bf(a.y); lo.z = f2bf(a.z); lo.w = f2bf(a.w);
        hi.x = f2bf(b.x); hi.y = f2bf(b.y); hi.z = f2bf(b.z); hi.w = f2bf(b.w);
        *(ushort4*)&Hs[m * 512 + sp * 8]     = lo;
        *(ushort4*)&Hs[m * 512 + sp * 8 + 4] = hi;
    }
    __syncthreads();

    // ---- edge-count scatter (u4 nibbles), once for both layers ----
    atomicAdd(&cntw[e1.x * 16 + (e0.x >> 3)], 1u << ((e0.x & 7) * 4));
    atomicAdd(&cntw[e1.y * 16 + (e0.y >> 3)], 1u << ((e0.y & 7) * 4));
    atomicAdd(&cntw[e1.z * 16 + (e0.z >> 3)], 1u << ((e0.z & 7) * 4));
    atomicAdd(&cntw[e1.w * 16 + (e0.w >> 3)], 1u << ((e0.w & 7) * 4));
    if (tid < 128) atomicAdd(&cntw[tid * 16 + (tid >> 3)], 1u << ((tid & 7) * 4));
    __syncthreads();

    for (int L = 0; L < 2; ++L) {
        const u16*  WL   = L ? W2b : W1b;
        const float* av_s = L ? a2s : a1s;
        const float* av_d = L ? a2d : a1d;

        // ---- GEMM: acc[i][j] = C[m=i*16.., f=w*64+j*16..]; W from register ring ----
        f32x4 acc[8][4] = {};
        {
            // lane's B-fragment: col f = w*64 + j*16 + rl, k = kt*32 + grp*8
            const u16* wg = WL + (size_t)(w * 64 + rl) * 512 + grp * 8;
            bf16x8 wreg[4];
            #pragma unroll
            for (int q = 0; q < 4; ++q)
                wreg[q] = *(const bf16x8*)&wg[(q & 3) * 16 * 512 + (q >> 2) * 32];
            for (int kt = 0; kt < 16; ++kt) {
                bf16x8 af[8];
                #pragma unroll
                for (int i = 0; i < 8; ++i) {
                    int m = i * 16 + rl;
                    int sp = (kt * 4 + grp) ^ (kt >> 1) ^ (m & 7);
                    af[i] = *(const bf16x8*)&Hs[m * 512 + sp * 8];
                }
                #pragma unroll
                for (int j = 0; j < 4; ++j) {
                    int q = kt * 4 + j;
                    bf16x8 bv = wreg[j];
                    if (q + 4 < 64) {
                        int qn = q + 4;
                        wreg[j] = *(const bf16x8*)&wg[(qn & 3) * 16 * 512 + (qn >> 2) * 32];
                    }
                    __builtin_amdgcn_s_setprio(1);
                    #pragma unroll
                    for (int i = 0; i < 8; ++i)
                        acc[i][j] = __builtin_amdgcn_mfma_f32_16x16x32_bf16(af[i], bv, acc[i][j], 0, 0, 0);
                    __builtin_amdgcn_s_setprio(0);
                }
            }
        }
        __syncthreads();   // all Hs(A) reads done -> safe to overwrite with H^T

        // ---- epilogue: H^T -> Hs (swizzled) + fused scores into stf ----
        {
            float asv[4], adv[4];
            #pragma unroll
            for (int j = 0; j < 4; ++j) {
                int f = w * 64 + j * 16 + rl;
                asv[j] = av_s[f]; adv[j] = av_d[f];
            }
            #pragma unroll
            for (int i = 0; i < 8; ++i) {
                #pragma unroll
                for (int j = 0; j < 4; ++j) {
                    int f = j * 16 + rl + w * 64;
                    int oct = i * 2 + (grp >> 1);
                    int elem = f * 128 + ((oct ^ (f & 15)) * 8) + (grp & 1) * 4;
                    ushort4 o;
                    o.x = f2bf(acc[i][j][0]); o.y = f2bf(acc[i][j][1]);
                    o.z = f2bf(acc[i][j][2]); o.w = f2bf(acc[i][j][3]);
                    *(ushort4*)&Hs[elem] = o;
                }
                #pragma unroll
                for (int r = 0; r < 4; ++r) {
                    float s = acc[i][0][r] * asv[0] + acc[i][1][r] * asv[1]
                            + acc[i][2][r] * asv[2] + acc[i][3][r] * asv[3];
                    float d = acc[i][0][r] * adv[0] + acc[i][1][r] * adv[1]
                            + acc[i][2][r] * adv[2] + acc[i][3][r] * adv[3];
                    #pragma unroll
                    for (int off = 1; off < 16; off <<= 1) {
                        s += __shfl_xor(s, off);
                        d += __shfl_xor(d, off);
                    }
                    if (rl == 0) {
                        int m = i * 16 + grp * 4 + r;
                        atomicAdd(&stf[m], s);
                        atomicAdd(&stf[128 + m], d);
                    }
                }
            }
        }
        __syncthreads();

        // ---- softmax stats M, 1/D per dst row ----
        for (int r = 0; r < 16; ++r) {
            int m = w * 16 + r;
            float sdm = stf[128 + m];
            u32 w0 = cntw[m * 16 + (lane >> 3)];
            u32 w1 = cntw[m * 16 + 8 + (lane >> 3)];
            u32 c0 = (w0 >> ((lane & 7) * 4)) & 15u;
            u32 c1 = (w1 >> ((lane & 7) * 4)) & 15u;
            float E0 = stf[lane] + sdm;      E0 = E0 > 0.f ? E0 : 0.2f * E0;
            float E1 = stf[lane + 64] + sdm; E1 = E1 > 0.f ? E1 : 0.2f * E1;
            float mx = fmaxf(c0 ? E0 : -1e30f, c1 ? E1 : -1e30f);
            #pragma unroll
            for (int off = 1; off < 64; off <<= 1) mx = fmaxf(mx, __shfl_xor(mx, off));
            float p = (c0 ? (float)c0 * __expf(E0 - mx) : 0.f)
                    + (c1 ? (float)c1 * __expf(E1 - mx) : 0.f);
            #pragma unroll
            for (int off = 1; off < 64; off <<= 1) p += __shfl_xor(p, off);
            if (lane == 0) { stf[256 + m] = mx; stf[384 + m] = 1.f / p; }
        }
        __syncthreads();

        // ---- alpha fragments (per-lane, from cnt + stats) ----
        int m = w * 16 + rl;
        float sdm = stf[128 + m], Mm = stf[256 + m], rDm = stf[384 + m];
        bf16x8 pa[4];
        #pragma unroll
        for (int kb = 0; kb < 4; ++kb) {
            u32 word = cntw[m * 16 + kb * 4 + grp];
            #pragma unroll
            for (int e = 0; e < 8; ++e) {
                u32 c = (word >> (e * 4)) & 15u;
                int s = kb * 32 + grp * 8 + e;
                float ev = stf[s] + sdm; ev = ev > 0.f ? ev : 0.2f * ev;
                float p = c ? (float)c * __expf(ev - Mm) * rDm : 0.f;
                pa[kb][e] = (__bf16)p;
            }
        }

        if (L == 0) {
            // ---- AGG1 (full acc; Hs write-after-read hazard) ----
            f32x4 acc2[32] = {};
            #pragma unroll
            for (int j = 0; j < 32; ++j) {
                int f = j * 16 + rl;
                #pragma unroll
                for (int kb = 0; kb < 4; ++kb) {
                    bf16x8 hb = *(const bf16x8*)&Hs[f * 128 + (((kb * 4 + grp) ^ rl) * 8)];
                    acc2[j] = __builtin_amdgcn_mfma_f32_16x16x32_bf16(pa[kb], hb, acc2[j], 0, 0, 0);
                }
            }
            __syncthreads();   // all H^T reads done before overwrite
            stf[tid] = 0.f;    // re-zero stats for layer-2 scores
            #pragma unroll
            for (int j = 0; j < 32; ++j) {
                int f = j * 16 + rl;
                float bv = b1[f];
                int slot = f >> 3;
                #pragma unroll
                for (int r = 0; r < 4; ++r) {
                    int m2 = w * 16 + grp * 4 + r;
                    int loc = slot ^ ((slot >> 3) & 7) ^ (m2 & 7);
                    Hs[m2 * 512 + loc * 8 + (f & 7)] = f2bf(gelu_f(acc2[j][r] + bv));
                }
            }
            __syncthreads();
        } else {
            // ---- AGG2: chunked acc, interleaved masked f32 stores ----
            float msk = (tt < valid[bb]) ? 1.f : 0.f;
            float* og = outF + (size_t)gid * 65536;
            #pragma unroll
            for (int jb = 0; jb < 4; ++jb) {
                f32x4 acc2[8] = {};
                #pragma unroll
                for (int j8 = 0; j8 < 8; ++j8) {
                    int f = (jb * 8 + j8) * 16 + rl;
                    #pragma unroll
                    for (int kb = 0; kb < 4; ++kb) {
                        bf16x8 hb = *(const bf16x8*)&Hs[f * 128 + (((kb * 4 + grp) ^ rl) * 8)];
                        acc2[j8] = __builtin_amdgcn_mfma_f32_16x16x32_bf16(pa[kb], hb, acc2[j8], 0, 0, 0);
                    }
                }
                #pragma unroll
                for (int j8 = 0; j8 < 8; ++j8) {
                    int f = (jb * 8 + j8) * 16 + rl;
                    float bv = b2[f];
                    #pragma unroll
                    for (int r = 0; r < 4; ++r) {
                        int m2 = w * 16 + grp * 4 + r;
                        og[m2 * 512 + f] = (acc2[j8][r] + bv) * msk;
                    }
                }
            }
        }
    }
}

// ---------------- time mix: out = gelu(W_time @ y + b_time) + y, in-place ----------------
__global__ __launch_bounds__(256) void timemix_kernel(float* __restrict__ y,
                                                      const float* __restrict__ Wt,
                                                      const float* __restrict__ bt) {
    __shared__ float wsm[1024];
    __shared__ float bts[32];
    int tid = threadIdx.x;
    for (int i = tid; i < 1024; i += 256) wsm[i] = Wt[i];
    if (tid < 32) bts[tid] = bt[tid];
    __syncthreads();
    int blk = blockIdx.x;               // 2048 blocks
    int b = blk >> 8;
    int rem = blk & 255;
    int n = rem >> 1;
    int f = (rem & 1) * 256 + tid;
    size_t base = ((size_t)b * 4096 + n) * 512 + f;
    float ys[32];
    #pragma unroll
    for (int s = 0; s < 32; ++s) ys[s] = y[base + (size_t)s * 65536];
    #pragma unroll
    for (int t = 0; t < 32; ++t) {
        float a = bts[t];
        #pragma unroll
        for (int s = 0; s < 32; ++s) a += wsm[t * 32 + s] * ys[s];
        y[base + (size_t)t * 65536] = gelu_f(a) + ys[t];
    }
}

extern "C" void kernel_launch(void* const* d_in, const int* in_sizes, int n_in,
                              void* d_out, int out_size, void* d_ws, size_t ws_size,
                              hipStream_t stream) {
    const float* x     = (const float*)d_in[0];
    const int*   ei    = (const int*)d_in[1];
    const int*   valid = (const int*)d_in[2];
    const float* W1    = (const float*)d_in[3];
    const float* a1s   = (const float*)d_in[4];
    const float* a1d   = (const float*)d_in[5];
    const float* b1    = (const float*)d_in[6];
    const float* W2    = (const float*)d_in[7];
    const float* a2s   = (const float*)d_in[8];
    const float* a2d   = (const float*)d_in[9];
    const float* b2    = (const float*)d_in[10];
    const float* Wt    = (const float*)d_in[11];
    const float* bt    = (const float*)d_in[12];
    float* out = (float*)d_out;

    char* ws = (char*)d_ws;
    u16* W1b = (u16*)(ws);            // 524,288 B (plain bf16 [f][k])
    u16* W2b = (u16*)(ws + 524288);   // 524,288 B

    prep_kernel<<<512, 256, 0, stream>>>(W1, W2, W1b, W2b);
    mega_kernel<<<256, 512, 0, stream>>>(x, ei, valid,
        W1b, a1s, a1d, b1, W2b, a2s, a2d, b2, out);
    timemix_kernel<<<2048, 256, 0, stream>>>(out, Wt, bt);
}

// Round 9
// 297.061 us; speedup vs baseline: 1.0210x; 1.0210x over previous
//
#include <hip/hip_runtime.h>

using u16 = unsigned short;
using u32 = unsigned int;

typedef __bf16 bf16x8 __attribute__((ext_vector_type(8)));
typedef float  f32x4  __attribute__((ext_vector_type(4)));

__device__ __forceinline__ u16 f2bf(float f) {
    u32 u = __float_as_uint(f);
    u32 r = u + 0x7fffu + ((u >> 16) & 1u);
    return (u16)(r >> 16);
}
__device__ __forceinline__ float gelu_f(float x) {
    return 0.5f * x * (1.0f + erff(x * 0.70710678118654752440f));
}

// ---------------- prep: cvt W1/W2 to plain bf16 [f][k] ----------------
__global__ __launch_bounds__(256) void prep_kernel(
    const float* __restrict__ W1, const float* __restrict__ W2,
    u16* __restrict__ W1b, u16* __restrict__ W2b)
{
    int i = blockIdx.x * 256 + threadIdx.x;          // 0..131071
    const float* src = (i < 65536) ? W1 : W2;
    u16* dst = (i < 65536) ? W1b : W2b;
    int ii = i & 65535;
    float4 v = ((const float4*)src)[ii];
    ushort4 o;
    o.x = f2bf(v.x); o.y = f2bf(v.y); o.z = f2bf(v.z); o.w = f2bf(v.w);
    ((ushort4*)dst)[ii] = o;
}

// ---------------- mega: full 2-layer GAT per graph, 1 block/graph, 8 waves ----------------
// LDS: Hs 128KB (x-bf16 -> H1^T -> H1' -> H2^T), SG 16KB:
//   [0,8K) cnt u4[128][128] packed in u32[128][16]
//   [8K,10K) stats f32[512]: ss[128] sd[128] M[128] rD[128]
// W operand comes from per-lane global loads (L2-resident) into a depth-4 register ring.
// waves_per_eu(2,2): LDS (144KB) caps us at 1 block/CU = 2 waves/SIMD anyway; pinning
// the allocator to that occupancy raises the VGPR budget 128 -> 256 (kills spills).
__global__ __attribute__((amdgpu_flat_work_group_size(512, 512), amdgpu_waves_per_eu(2, 2)))
void mega_kernel(
    const float* __restrict__ x, const int* __restrict__ ei, const int* __restrict__ valid,
    const u16* __restrict__ W1b, const float* __restrict__ a1s, const float* __restrict__ a1d,
    const float* __restrict__ b1,
    const u16* __restrict__ W2b, const float* __restrict__ a2s, const float* __restrict__ a2d,
    const float* __restrict__ b2,
    float* __restrict__ outF)
{
    __shared__ u16 Hs[65536];
    __shared__ __align__(16) u16 SG[8192];
    u32*   cntw = (u32*)SG;                 // [0, 8K) bytes
    float* stf  = (float*)(SG + 4096);      // [8K, 10K) bytes

    const int tid  = threadIdx.x;
    const int lane = tid & 63;
    const int w    = tid >> 6;
    const int rl   = lane & 15;
    const int grp  = lane >> 4;
    const int gid  = blockIdx.x;
    const int bb   = gid >> 5, tt = gid & 31;

    // ---- phase 0: edge prefetch, cnt/stats zero, x -> bf16 Hs (swizzled) ----
    const int4* es = (const int4*)(ei + (size_t)gid * 4096);
    int4 e0 = es[tid], e1 = es[512 + tid];

    for (int i = tid; i < 2048; i += 512) cntw[i] = 0u;
    stf[tid] = 0.f;

    const float4* xg = (const float4*)(x + (size_t)gid * 65536);
    #pragma unroll
    for (int it = 0; it < 16; ++it) {
        float4 a = xg[tid * 2 + it * 1024];
        float4 b = xg[tid * 2 + 1 + it * 1024];
        int m = it * 8 + w;
        int sp = lane ^ ((lane >> 3) & 7) ^ (m & 7);
        ushort4 lo, hi;
        lo.x = f2bf(a.x); lo.y = f2bf(a.y); lo.z = f2bf(a.z); lo.w = f2bf(a.w);
        hi.x = f2bf(b.x); hi.y = f2bf(b.y); hi.z = f2bf(b.z); hi.w = f2bf(b.w);
        *(ushort4*)&Hs[m * 512 + sp * 8]     = lo;
        *(ushort4*)&Hs[m * 512 + sp * 8 + 4] = hi;
    }
    __syncthreads();

    // ---- edge-count scatter (u4 nibbles), once for both layers ----
    atomicAdd(&cntw[e1.x * 16 + (e0.x >> 3)], 1u << ((e0.x & 7) * 4));
    atomicAdd(&cntw[e1.y * 16 + (e0.y >> 3)], 1u << ((e0.y & 7) * 4));
    atomicAdd(&cntw[e1.z * 16 + (e0.z >> 3)], 1u << ((e0.z & 7) * 4));
    atomicAdd(&cntw[e1.w * 16 + (e0.w >> 3)], 1u << ((e0.w & 7) * 4));
    if (tid < 128) atomicAdd(&cntw[tid * 16 + (tid >> 3)], 1u << ((tid & 7) * 4));
    __syncthreads();

    for (int L = 0; L < 2; ++L) {
        const u16*  WL   = L ? W2b : W1b;
        const float* av_s = L ? a2s : a1s;
        const float* av_d = L ? a2d : a1d;

        // ---- GEMM: acc[i][j] = C[m=i*16.., f=w*64+j*16..]; W from register ring ----
        f32x4 acc[8][4] = {};
        {
            // lane's B-fragment: col f = w*64 + j*16 + rl, k = kt*32 + grp*8
            const u16* wg = WL + (size_t)(w * 64 + rl) * 512 + grp * 8;
            bf16x8 wreg[4];
            #pragma unroll
            for (int q = 0; q < 4; ++q)
                wreg[q] = *(const bf16x8*)&wg[(q & 3) * 16 * 512 + (q >> 2) * 32];
            for (int kt = 0; kt < 16; ++kt) {
                bf16x8 af[8];
                #pragma unroll
                for (int i = 0; i < 8; ++i) {
                    int m = i * 16 + rl;
                    int sp = (kt * 4 + grp) ^ (kt >> 1) ^ (m & 7);
                    af[i] = *(const bf16x8*)&Hs[m * 512 + sp * 8];
                }
                #pragma unroll
                for (int j = 0; j < 4; ++j) {
                    int q = kt * 4 + j;
                    bf16x8 bv = wreg[j];
                    if (q + 4 < 64) {
                        int qn = q + 4;
                        wreg[j] = *(const bf16x8*)&wg[(qn & 3) * 16 * 512 + (qn >> 2) * 32];
                    }
                    __builtin_amdgcn_s_setprio(1);
                    #pragma unroll
                    for (int i = 0; i < 8; ++i)
                        acc[i][j] = __builtin_amdgcn_mfma_f32_16x16x32_bf16(af[i], bv, acc[i][j], 0, 0, 0);
                    __builtin_amdgcn_s_setprio(0);
                }
            }
        }
        __syncthreads();   // all Hs(A) reads done -> safe to overwrite with H^T

        // ---- epilogue: H^T -> Hs (swizzled) + fused scores into stf ----
        {
            float asv[4], adv[4];
            #pragma unroll
            for (int j = 0; j < 4; ++j) {
                int f = w * 64 + j * 16 + rl;
                asv[j] = av_s[f]; adv[j] = av_d[f];
            }
            #pragma unroll
            for (int i = 0; i < 8; ++i) {
                #pragma unroll
                for (int j = 0; j < 4; ++j) {
                    int f = j * 16 + rl + w * 64;
                    int oct = i * 2 + (grp >> 1);
                    int elem = f * 128 + ((oct ^ (f & 15)) * 8) + (grp & 1) * 4;
                    ushort4 o;
                    o.x = f2bf(acc[i][j][0]); o.y = f2bf(acc[i][j][1]);
                    o.z = f2bf(acc[i][j][2]); o.w = f2bf(acc[i][j][3]);
                    *(ushort4*)&Hs[elem] = o;
                }
                #pragma unroll
                for (int r = 0; r < 4; ++r) {
                    float s = acc[i][0][r] * asv[0] + acc[i][1][r] * asv[1]
                            + acc[i][2][r] * asv[2] + acc[i][3][r] * asv[3];
                    float d = acc[i][0][r] * adv[0] + acc[i][1][r] * adv[1]
                            + acc[i][2][r] * adv[2] + acc[i][3][r] * adv[3];
                    #pragma unroll
                    for (int off = 1; off < 16; off <<= 1) {
                        s += __shfl_xor(s, off);
                        d += __shfl_xor(d, off);
                    }
                    if (rl == 0) {
                        int m = i * 16 + grp * 4 + r;
                        atomicAdd(&stf[m], s);
                        atomicAdd(&stf[128 + m], d);
                    }
                }
            }
        }
        __syncthreads();

        // ---- softmax stats M, 1/D per dst row ----
        for (int r = 0; r < 16; ++r) {
            int m = w * 16 + r;
            float sdm = stf[128 + m];
            u32 w0 = cntw[m * 16 + (lane >> 3)];
            u32 w1 = cntw[m * 16 + 8 + (lane >> 3)];
            u32 c0 = (w0 >> ((lane & 7) * 4)) & 15u;
            u32 c1 = (w1 >> ((lane & 7) * 4)) & 15u;
            float E0 = stf[lane] + sdm;      E0 = E0 > 0.f ? E0 : 0.2f * E0;
            float E1 = stf[lane + 64] + sdm; E1 = E1 > 0.f ? E1 : 0.2f * E1;
            float mx = fmaxf(c0 ? E0 : -1e30f, c1 ? E1 : -1e30f);
            #pragma unroll
            for (int off = 1; off < 64; off <<= 1) mx = fmaxf(mx, __shfl_xor(mx, off));
            float p = (c0 ? (float)c0 * __expf(E0 - mx) : 0.f)
                    + (c1 ? (float)c1 * __expf(E1 - mx) : 0.f);
            #pragma unroll
            for (int off = 1; off < 64; off <<= 1) p += __shfl_xor(p, off);
            if (lane == 0) { stf[256 + m] = mx; stf[384 + m] = 1.f / p; }
        }
        __syncthreads();

        // ---- alpha fragments (per-lane, from cnt + stats) ----
        int m = w * 16 + rl;
        float sdm = stf[128 + m], Mm = stf[256 + m], rDm = stf[384 + m];
        bf16x8 pa[4];
        #pragma unroll
        for (int kb = 0; kb < 4; ++kb) {
            u32 word = cntw[m * 16 + kb * 4 + grp];
            #pragma unroll
            for (int e = 0; e < 8; ++e) {
                u32 c = (word >> (e * 4)) & 15u;
                int s = kb * 32 + grp * 8 + e;
                float ev = stf[s] + sdm; ev = ev > 0.f ? ev : 0.2f * ev;
                float p = c ? (float)c * __expf(ev - Mm) * rDm : 0.f;
                pa[kb][e] = (__bf16)p;
            }
        }

        if (L == 0) {
            // ---- AGG1 (full acc; Hs write-after-read hazard) ----
            f32x4 acc2[32] = {};
            #pragma unroll
            for (int j = 0; j < 32; ++j) {
                int f = j * 16 + rl;
                #pragma unroll
                for (int kb = 0; kb < 4; ++kb) {
                    bf16x8 hb = *(const bf16x8*)&Hs[f * 128 + (((kb * 4 + grp) ^ rl) * 8)];
                    acc2[j] = __builtin_amdgcn_mfma_f32_16x16x32_bf16(pa[kb], hb, acc2[j], 0, 0, 0);
                }
            }
            __syncthreads();   // all H^T reads done before overwrite
            stf[tid] = 0.f;    // re-zero stats for layer-2 scores
            #pragma unroll
            for (int j = 0; j < 32; ++j) {
                int f = j * 16 + rl;
                float bv = b1[f];
                int slot = f >> 3;
                #pragma unroll
                for (int r = 0; r < 4; ++r) {
                    int m2 = w * 16 + grp * 4 + r;
                    int loc = slot ^ ((slot >> 3) & 7) ^ (m2 & 7);
                    Hs[m2 * 512 + loc * 8 + (f & 7)] = f2bf(gelu_f(acc2[j][r] + bv));
                }
            }
            __syncthreads();
        } else {
            // ---- AGG2: chunked acc, interleaved masked f32 stores ----
            float msk = (tt < valid[bb]) ? 1.f : 0.f;
            float* og = outF + (size_t)gid * 65536;
            #pragma unroll
            for (int jb = 0; jb < 4; ++jb) {
                f32x4 acc2[8] = {};
                #pragma unroll
                for (int j8 = 0; j8 < 8; ++j8) {
                    int f = (jb * 8 + j8) * 16 + rl;
                    #pragma unroll
                    for (int kb = 0; kb < 4; ++kb) {
                        bf16x8 hb = *(const bf16x8*)&Hs[f * 128 + (((kb * 4 + grp) ^ rl) * 8)];
                        acc2[j8] = __builtin_amdgcn_mfma_f32_16x16x32_bf16(pa[kb], hb, acc2[j8], 0, 0, 0);
                    }
                }
                #pragma unroll
                for (int j8 = 0; j8 < 8; ++j8) {
                    int f = (jb * 8 + j8) * 16 + rl;
                    float bv = b2[f];
                    #pragma unroll
                    for (int r = 0; r < 4; ++r) {
                        int m2 = w * 16 + grp * 4 + r;
                        og[m2 * 512 + f] = (acc2[j8][r] + bv) * msk;
                    }
                }
            }
        }
    }
}

// ---------------- time mix: out = gelu(W_time @ y + b_time) + y, in-place ----------------
__global__ __launch_bounds__(256) void timemix_kernel(float* __restrict__ y,
                                                      const float* __restrict__ Wt,
                                                      const float* __restrict__ bt) {
    __shared__ float wsm[1024];
    __shared__ float bts[32];
    int tid = threadIdx.x;
    for (int i = tid; i < 1024; i += 256) wsm[i] = Wt[i];
    if (tid < 32) bts[tid] = bt[tid];
    __syncthreads();
    int blk = blockIdx.x;               // 2048 blocks
    int b = blk >> 8;
    int rem = blk & 255;
    int n = rem >> 1;
    int f = (rem & 1) * 256 + tid;
    size_t base = ((size_t)b * 4096 + n) * 512 + f;
    float ys[32];
    #pragma unroll
    for (int s = 0; s < 32; ++s) ys[s] = y[base + (size_t)s * 65536];
    #pragma unroll
    for (int t = 0; t < 32; ++t) {
        float a = bts[t];
        #pragma unroll
        for (int s = 0; s < 32; ++s) a += wsm[t * 32 + s] * ys[s];
        y[base + (size_t)t * 65536] = gelu_f(a) + ys[t];
    }
}

extern "C" void kernel_launch(void* const* d_in, const int* in_sizes, int n_in,
                              void* d_out, int out_size, void* d_ws, size_t ws_size,
                              hipStream_t stream) {
    const float* x     = (const float*)d_in[0];
    const int*   ei    = (const int*)d_in[1];
    const int*   valid = (const int*)d_in[2];
    const float* W1    = (const float*)d_in[3];
    const float* a1s   = (const float*)d_in[4];
    const float* a1d   = (const float*)d_in[5];
    const float* b1    = (const float*)d_in[6];
    const float* W2    = (const float*)d_in[7];
    const float* a2s   = (const float*)d_in[8];
    const float* a2d   = (const float*)d_in[9];
    const float* b2    = (const float*)d_in[10];
    const float* Wt    = (const float*)d_in[11];
    const float* bt    = (const float*)d_in[12];
    float* out = (float*)d_out;

    char* ws = (char*)d_ws;
    u16* W1b = (u16*)(ws);            // 524,288 B (plain bf16 [f][k])
    u16* W2b = (u16*)(ws + 524288);   // 524,288 B

    prep_kernel<<<512, 256, 0, stream>>>(W1, W2, W1b, W2b);
    mega_kernel<<<256, 512, 0, stream>>>(x, ei, valid,
        W1b, a1s, a1d, b1, W2b, a2s, a2d, b2, out);
    timemix_kernel<<<2048, 256, 0, stream>>>(out, Wt, bt);
}

// Round 10
// 273.854 us; speedup vs baseline: 1.1075x; 1.0847x over previous
//
#include <hip/hip_runtime.h>

using u16 = unsigned short;
using u32 = unsigned int;

typedef __bf16 bf16x8 __attribute__((ext_vector_type(8)));
typedef float  f32x4  __attribute__((ext_vector_type(4)));

__device__ __forceinline__ u16 f2bf(float f) {
    u32 u = __float_as_uint(f);
    u32 r = u + 0x7fffu + ((u >> 16) & 1u);
    return (u16)(r >> 16);
}
__device__ __forceinline__ float gelu_f(float x) {
    return 0.5f * x * (1.0f + erff(x * 0.70710678118654752440f));
}

// ---------------- prep: cvt W1/W2 to plain bf16 [f][k] ----------------
__global__ __launch_bounds__(256) void prep_kernel(
    const float* __restrict__ W1, const float* __restrict__ W2,
    u16* __restrict__ W1b, u16* __restrict__ W2b)
{
    int i = blockIdx.x * 256 + threadIdx.x;          // 0..131071
    const float* src = (i < 65536) ? W1 : W2;
    u16* dst = (i < 65536) ? W1b : W2b;
    int ii = i & 65535;
    float4 v = ((const float4*)src)[ii];
    ushort4 o;
    o.x = f2bf(v.x); o.y = f2bf(v.y); o.z = f2bf(v.z); o.w = f2bf(v.w);
    ((ushort4*)dst)[ii] = o;
}

// ---------------- mega: full 2-layer GAT per graph, 1 block/graph, 8 waves ----------------
// LDS: Hs 128KB (x-bf16 -> H1^T -> H1' -> H2^T), SG 16KB:
//   [0,8K) cnt u4[128][128] packed in u32[128][16]
//   [8K,10K) stats f32[512]: ss[128] sd[128] M[128] rD[128]
// Register-pressure discipline (arch half capped at 128 by accum_offset split):
//   - x staging: #pragma unroll 2 (prevents 32x float4 load hoist)
//   - GEMM k-loop: one af fragment live; wA/wB W double-buffer; ktp loop kept rolled
__global__ __attribute__((amdgpu_flat_work_group_size(512, 512), amdgpu_waves_per_eu(2, 2)))
void mega_kernel(
    const float* __restrict__ x, const int* __restrict__ ei, const int* __restrict__ valid,
    const u16* __restrict__ W1b, const float* __restrict__ a1s, const float* __restrict__ a1d,
    const float* __restrict__ b1,
    const u16* __restrict__ W2b, const float* __restrict__ a2s, const float* __restrict__ a2d,
    const float* __restrict__ b2,
    float* __restrict__ outF)
{
    __shared__ u16 Hs[65536];
    __shared__ __align__(16) u16 SG[8192];
    u32*   cntw = (u32*)SG;                 // [0, 8K) bytes
    float* stf  = (float*)(SG + 4096);      // [8K, 10K) bytes

    const int tid  = threadIdx.x;
    const int lane = tid & 63;
    const int w    = tid >> 6;
    const int rl   = lane & 15;
    const int grp  = lane >> 4;
    const int gid  = blockIdx.x;
    const int bb   = gid >> 5, tt = gid & 31;

    // ---- phase 0: edge prefetch, cnt/stats zero, x -> bf16 Hs (swizzled) ----
    const int4* es = (const int4*)(ei + (size_t)gid * 4096);
    int4 e0 = es[tid], e1 = es[512 + tid];

    for (int i = tid; i < 2048; i += 512) cntw[i] = 0u;
    stf[tid] = 0.f;

    const float4* xg = (const float4*)(x + (size_t)gid * 65536);
    #pragma unroll 2
    for (int it = 0; it < 16; ++it) {
        float4 a = xg[tid * 2 + it * 1024];
        float4 b = xg[tid * 2 + 1 + it * 1024];
        int m = it * 8 + w;
        int sp = lane ^ ((lane >> 3) & 7) ^ (m & 7);
        ushort4 lo, hi;
        lo.x = f2bf(a.x); lo.y = f2bf(a.y); lo.z = f2bf(a.z); lo.w = f2bf(a.w);
        hi.x = f2bf(b.x); hi.y = f2bf(b.y); hi.z = f2bf(b.z); hi.w = f2bf(b.w);
        *(ushort4*)&Hs[m * 512 + sp * 8]     = lo;
        *(ushort4*)&Hs[m * 512 + sp * 8 + 4] = hi;
    }
    __syncthreads();

    // ---- edge-count scatter (u4 nibbles), once for both layers ----
    atomicAdd(&cntw[e1.x * 16 + (e0.x >> 3)], 1u << ((e0.x & 7) * 4));
    atomicAdd(&cntw[e1.y * 16 + (e0.y >> 3)], 1u << ((e0.y & 7) * 4));
    atomicAdd(&cntw[e1.z * 16 + (e0.z >> 3)], 1u << ((e0.z & 7) * 4));
    atomicAdd(&cntw[e1.w * 16 + (e0.w >> 3)], 1u << ((e0.w & 7) * 4));
    if (tid < 128) atomicAdd(&cntw[tid * 16 + (tid >> 3)], 1u << ((tid & 7) * 4));
    __syncthreads();

    for (int L = 0; L < 2; ++L) {
        const u16*  WL   = L ? W2b : W1b;
        const float* av_s = L ? a2s : a1s;
        const float* av_d = L ? a2d : a1d;

        // ---- GEMM: acc[i][j] = C[m=i*16.., f=w*64+j*16..] ----
        f32x4 acc[8][4] = {};
        {
            // lane's W fragment for (kt,j): wg[j*8192 + kt*32]
            const u16* wg = WL + (size_t)(w * 64 + rl) * 512 + grp * 8;
            bf16x8 wA[4], wB[4];
            #pragma unroll
            for (int j = 0; j < 4; ++j) wA[j] = *(const bf16x8*)&wg[j * 8192];
            #pragma unroll
            for (int j = 0; j < 4; ++j) wB[j] = *(const bf16x8*)&wg[j * 8192 + 32];
            #pragma unroll 1
            for (int ktp = 0; ktp < 8; ++ktp) {
                const int kt0 = ktp * 2, kt1 = kt0 + 1;
                // --- kt0: consume wA ---
                __builtin_amdgcn_s_setprio(1);
                #pragma unroll
                for (int i = 0; i < 8; ++i) {
                    int m = i * 16 + rl;
                    int sp = (kt0 * 4 + grp) ^ (ktp & 7) ^ (m & 7);
                    bf16x8 af = *(const bf16x8*)&Hs[m * 512 + sp * 8];
                    #pragma unroll
                    for (int j = 0; j < 4; ++j)
                        acc[i][j] = __builtin_amdgcn_mfma_f32_16x16x32_bf16(af, wA[j], acc[i][j], 0, 0, 0);
                }
                __builtin_amdgcn_s_setprio(0);
                if (ktp < 7) {
                    #pragma unroll
                    for (int j = 0; j < 4; ++j)
                        wA[j] = *(const bf16x8*)&wg[j * 8192 + (kt0 + 2) * 32];
                }
                // --- kt1: consume wB ---
                __builtin_amdgcn_s_setprio(1);
                #pragma unroll
                for (int i = 0; i < 8; ++i) {
                    int m = i * 16 + rl;
                    int sp = (kt1 * 4 + grp) ^ (kt1 >> 1) ^ (m & 7);
                    bf16x8 af = *(const bf16x8*)&Hs[m * 512 + sp * 8];
                    #pragma unroll
                    for (int j = 0; j < 4; ++j)
                        acc[i][j] = __builtin_amdgcn_mfma_f32_16x16x32_bf16(af, wB[j], acc[i][j], 0, 0, 0);
                }
                __builtin_amdgcn_s_setprio(0);
                if (ktp < 7) {
                    #pragma unroll
                    for (int j = 0; j < 4; ++j)
                        wB[j] = *(const bf16x8*)&wg[j * 8192 + (kt1 + 2) * 32];
                }
            }
        }
        __syncthreads();   // all Hs(A) reads done -> safe to overwrite with H^T

        // ---- epilogue: H^T -> Hs (swizzled) + fused scores into stf ----
        {
            float asv[4], adv[4];
            #pragma unroll
            for (int j = 0; j < 4; ++j) {
                int f = w * 64 + j * 16 + rl;
                asv[j] = av_s[f]; adv[j] = av_d[f];
            }
            #pragma unroll
            for (int i = 0; i < 8; ++i) {
                #pragma unroll
                for (int j = 0; j < 4; ++j) {
                    int f = j * 16 + rl + w * 64;
                    int oct = i * 2 + (grp >> 1);
                    int elem = f * 128 + ((oct ^ (f & 15)) * 8) + (grp & 1) * 4;
                    ushort4 o;
                    o.x = f2bf(acc[i][j][0]); o.y = f2bf(acc[i][j][1]);
                    o.z = f2bf(acc[i][j][2]); o.w = f2bf(acc[i][j][3]);
                    *(ushort4*)&Hs[elem] = o;
                }
                #pragma unroll
                for (int r = 0; r < 4; ++r) {
                    float s = acc[i][0][r] * asv[0] + acc[i][1][r] * asv[1]
                            + acc[i][2][r] * asv[2] + acc[i][3][r] * asv[3];
                    float d = acc[i][0][r] * adv[0] + acc[i][1][r] * adv[1]
                            + acc[i][2][r] * adv[2] + acc[i][3][r] * adv[3];
                    #pragma unroll
                    for (int off = 1; off < 16; off <<= 1) {
                        s += __shfl_xor(s, off);
                        d += __shfl_xor(d, off);
                    }
                    if (rl == 0) {
                        int m = i * 16 + grp * 4 + r;
                        atomicAdd(&stf[m], s);
                        atomicAdd(&stf[128 + m], d);
                    }
                }
            }
        }
        __syncthreads();

        // ---- softmax stats M, 1/D per dst row ----
        for (int r = 0; r < 16; ++r) {
            int m = w * 16 + r;
            float sdm = stf[128 + m];
            u32 w0 = cntw[m * 16 + (lane >> 3)];
            u32 w1 = cntw[m * 16 + 8 + (lane >> 3)];
            u32 c0 = (w0 >> ((lane & 7) * 4)) & 15u;
            u32 c1 = (w1 >> ((lane & 7) * 4)) & 15u;
            float E0 = stf[lane] + sdm;      E0 = E0 > 0.f ? E0 : 0.2f * E0;
            float E1 = stf[lane + 64] + sdm; E1 = E1 > 0.f ? E1 : 0.2f * E1;
            float mx = fmaxf(c0 ? E0 : -1e30f, c1 ? E1 : -1e30f);
            #pragma unroll
            for (int off = 1; off < 64; off <<= 1) mx = fmaxf(mx, __shfl_xor(mx, off));
            float p = (c0 ? (float)c0 * __expf(E0 - mx) : 0.f)
                    + (c1 ? (float)c1 * __expf(E1 - mx) : 0.f);
            #pragma unroll
            for (int off = 1; off < 64; off <<= 1) p += __shfl_xor(p, off);
            if (lane == 0) { stf[256 + m] = mx; stf[384 + m] = 1.f / p; }
        }
        __syncthreads();

        // ---- alpha fragments (per-lane, from cnt + stats) ----
        int m = w * 16 + rl;
        float sdm = stf[128 + m], Mm = stf[256 + m], rDm = stf[384 + m];
        bf16x8 pa[4];
        #pragma unroll
        for (int kb = 0; kb < 4; ++kb) {
            u32 word = cntw[m * 16 + kb * 4 + grp];
            #pragma unroll
            for (int e = 0; e < 8; ++e) {
                u32 c = (word >> (e * 4)) & 15u;
                int s = kb * 32 + grp * 8 + e;
                float ev = stf[s] + sdm; ev = ev > 0.f ? ev : 0.2f * ev;
                float p = c ? (float)c * __expf(ev - Mm) * rDm : 0.f;
                pa[kb][e] = (__bf16)p;
            }
        }

        if (L == 0) {
            // ---- AGG1 (full acc; Hs write-after-read hazard) ----
            f32x4 acc2[32] = {};
            #pragma unroll
            for (int j = 0; j < 32; ++j) {
                int f = j * 16 + rl;
                #pragma unroll
                for (int kb = 0; kb < 4; ++kb) {
                    bf16x8 hb = *(const bf16x8*)&Hs[f * 128 + (((kb * 4 + grp) ^ rl) * 8)];
                    acc2[j] = __builtin_amdgcn_mfma_f32_16x16x32_bf16(pa[kb], hb, acc2[j], 0, 0, 0);
                }
            }
            __syncthreads();   // all H^T reads done before overwrite
            stf[tid] = 0.f;    // re-zero stats for layer-2 scores
            #pragma unroll
            for (int j = 0; j < 32; ++j) {
                int f = j * 16 + rl;
                float bv = b1[f];
                int slot = f >> 3;
                #pragma unroll
                for (int r = 0; r < 4; ++r) {
                    int m2 = w * 16 + grp * 4 + r;
                    int loc = slot ^ ((slot >> 3) & 7) ^ (m2 & 7);
                    Hs[m2 * 512 + loc * 8 + (f & 7)] = f2bf(gelu_f(acc2[j][r] + bv));
                }
            }
            __syncthreads();
        } else {
            // ---- AGG2: chunked acc, interleaved masked f32 stores ----
            float msk = (tt < valid[bb]) ? 1.f : 0.f;
            float* og = outF + (size_t)gid * 65536;
            #pragma unroll
            for (int jb = 0; jb < 4; ++jb) {
                f32x4 acc2[8] = {};
                #pragma unroll
                for (int j8 = 0; j8 < 8; ++j8) {
                    int f = (jb * 8 + j8) * 16 + rl;
                    #pragma unroll
                    for (int kb = 0; kb < 4; ++kb) {
                        bf16x8 hb = *(const bf16x8*)&Hs[f * 128 + (((kb * 4 + grp) ^ rl) * 8)];
                        acc2[j8] = __builtin_amdgcn_mfma_f32_16x16x32_bf16(pa[kb], hb, acc2[j8], 0, 0, 0);
                    }
                }
                #pragma unroll
                for (int j8 = 0; j8 < 8; ++j8) {
                    int f = (jb * 8 + j8) * 16 + rl;
                    float bv = b2[f];
                    #pragma unroll
                    for (int r = 0; r < 4; ++r) {
                        int m2 = w * 16 + grp * 4 + r;
                        og[m2 * 512 + f] = (acc2[j8][r] + bv) * msk;
                    }
                }
            }
        }
    }
}

// ---------------- time mix: out = gelu(W_time @ y + b_time) + y, in-place ----------------
__global__ __launch_bounds__(256) void timemix_kernel(float* __restrict__ y,
                                                      const float* __restrict__ Wt,
                                                      const float* __restrict__ bt) {
    __shared__ float wsm[1024];
    __shared__ float bts[32];
    int tid = threadIdx.x;
    for (int i = tid; i < 1024; i += 256) wsm[i] = Wt[i];
    if (tid < 32) bts[tid] = bt[tid];
    __syncthreads();
    int blk = blockIdx.x;               // 2048 blocks
    int b = blk >> 8;
    int rem = blk & 255;
    int n = rem >> 1;
    int f = (rem & 1) * 256 + tid;
    size_t base = ((size_t)b * 4096 + n) * 512 + f;
    float ys[32];
    #pragma unroll
    for (int s = 0; s < 32; ++s) ys[s] = y[base + (size_t)s * 65536];
    #pragma unroll
    for (int t = 0; t < 32; ++t) {
        float a = bts[t];
        #pragma unroll
        for (int s = 0; s < 32; ++s) a += wsm[t * 32 + s] * ys[s];
        y[base + (size_t)t * 65536] = gelu_f(a) + ys[t];
    }
}

extern "C" void kernel_launch(void* const* d_in, const int* in_sizes, int n_in,
                              void* d_out, int out_size, void* d_ws, size_t ws_size,
                              hipStream_t stream) {
    const float* x     = (const float*)d_in[0];
    const int*   ei    = (const int*)d_in[1];
    const int*   valid = (const int*)d_in[2];
    const float* W1    = (const float*)d_in[3];
    const float* a1s   = (const float*)d_in[4];
    const float* a1d   = (const float*)d_in[5];
    const float* b1    = (const float*)d_in[6];
    const float* W2    = (const float*)d_in[7];
    const float* a2s   = (const float*)d_in[8];
    const float* a2d   = (const float*)d_in[9];
    const float* b2    = (const float*)d_in[10];
    const float* Wt    = (const float*)d_in[11];
    const float* bt    = (const float*)d_in[12];
    float* out = (float*)d_out;

    char* ws = (char*)d_ws;
    u16* W1b = (u16*)(ws);            // 524,288 B (plain bf16 [f][k])
    u16* W2b = (u16*)(ws + 524288);   // 524,288 B

    prep_kernel<<<512, 256, 0, stream>>>(W1, W2, W1b, W2b);
    mega_kernel<<<256, 512, 0, stream>>>(x, ei, valid,
        W1b, a1s, a1d, b1, W2b, a2s, a2d, b2, out);
    timemix_kernel<<<2048, 256, 0, stream>>>(out, Wt, bt);
}

// Round 11
// 220.234 us; speedup vs baseline: 1.3772x; 1.2435x over previous
//
#include <hip/hip_runtime.h>

using u16 = unsigned short;
using u32 = unsigned int;

typedef __bf16 bf16x8 __attribute__((ext_vector_type(8)));
typedef float  f32x4  __attribute__((ext_vector_type(4)));

__device__ __forceinline__ u16 f2bf(float f) {
    u32 u = __float_as_uint(f);
    u32 r = u + 0x7fffu + ((u >> 16) & 1u);
    return (u16)(r >> 16);
}
__device__ __forceinline__ float gelu_f(float x) {
    return 0.5f * x * (1.0f + erff(x * 0.70710678118654752440f));
}

#define GLOAD16(gp, lp) __builtin_amdgcn_global_load_lds( \
    (const __attribute__((address_space(1))) void*)(gp),  \
    (__attribute__((address_space(3))) void*)(lp), 16, 0, 0)

// ---------------- prep: cvt x -> bf16 Xb, zero score buffers ----------------
__global__ __launch_bounds__(256) void prep_kernel(
    const float* __restrict__ x, u16* __restrict__ Xb, float* __restrict__ Z)
{
    const int i0 = blockIdx.x * 256 + threadIdx.x;
    const int stride = gridDim.x * 256;
    if (i0 < 32768) ((float4*)Z)[i0] = make_float4(0.f, 0.f, 0.f, 0.f);
    for (int i = i0; i < 4194304; i += stride) {
        float4 v = ((const float4*)x)[i];
        ushort4 o;
        o.x = f2bf(v.x); o.y = f2bf(v.y); o.z = f2bf(v.z); o.w = f2bf(v.w);
        ((ushort4*)Xb)[i] = o;
    }
}

// ---------------- kernel A: GEMM + H^T + scores, one block per (graph, f-half) ----------------
// A[g][128][512] bf16, W[512][512] f32 (L2-hot). Block: 8 waves; wave tile 128m x 32f.
// acc[8][2] = 64 regs. A-tile [128][32] bf16 double-buffered (16KB), GLOAD16-staged.
__global__ __launch_bounds__(512) void gat_gemm(
    const u16* __restrict__ A, const float* __restrict__ W,
    const float* __restrict__ a_s, const float* __restrict__ a_d,
    u16* __restrict__ HT, float* __restrict__ SS, float* __restrict__ SD)
{
    __shared__ __align__(16) u16 As[2][128 * 32];
    __shared__ float sA[128], dA[128];

    const int tid  = threadIdx.x;
    const int lane = tid & 63;
    const int w    = tid >> 6;
    const int rl   = lane & 15;
    const int grp  = lane >> 4;
    const int g    = blockIdx.x >> 1;
    const int hf   = blockIdx.x & 1;

    if (tid < 128) { sA[tid] = 0.f; dA[tid] = 0.f; }

    const u16* Ag   = A + (size_t)g * 65536;
    const u16* asrc = Ag + (size_t)(w * 16 + (lane >> 2)) * 512 + (lane & 3) * 8;
    const float* wg = W + (size_t)(hf * 256 + w * 32 + rl) * 512 + grp * 8;

    float4 wf0[2], wf1[2];
    wf0[0] = *(const float4*)&wg[0];     wf1[0] = *(const float4*)&wg[4];
    wf0[1] = *(const float4*)&wg[8192];  wf1[1] = *(const float4*)&wg[8192 + 4];

    GLOAD16(asrc, &As[0][w * 512]);
    __syncthreads();

    f32x4 acc[8][2] = {};
    int buf = 0;
    for (int kt = 0; kt < 16; ++kt) {
        if (kt < 15) GLOAD16(asrc + (kt + 1) * 32, &As[buf ^ 1][w * 512]);
        bf16x8 wb[2];
        #pragma unroll
        for (int j = 0; j < 2; ++j) {
            float4 lo = wf0[j], hi = wf1[j];
            wb[j][0] = (__bf16)lo.x; wb[j][1] = (__bf16)lo.y;
            wb[j][2] = (__bf16)lo.z; wb[j][3] = (__bf16)lo.w;
            wb[j][4] = (__bf16)hi.x; wb[j][5] = (__bf16)hi.y;
            wb[j][6] = (__bf16)hi.z; wb[j][7] = (__bf16)hi.w;
        }
        if (kt < 15) {
            #pragma unroll
            for (int j = 0; j < 2; ++j) {
                wf0[j] = *(const float4*)&wg[j * 8192 + (kt + 1) * 32];
                wf1[j] = *(const float4*)&wg[j * 8192 + (kt + 1) * 32 + 4];
            }
        }
        #pragma unroll
        for (int i = 0; i < 8; ++i) {
            bf16x8 af = *(const bf16x8*)&As[buf][(i * 16 + rl) * 32 + grp * 8];
            acc[i][0] = __builtin_amdgcn_mfma_f32_16x16x32_bf16(af, wb[0], acc[i][0], 0, 0, 0);
            acc[i][1] = __builtin_amdgcn_mfma_f32_16x16x32_bf16(af, wb[1], acc[i][1], 0, 0, 0);
        }
        __syncthreads();
        buf ^= 1;
    }

    // ---- epilogue: H^T write + fused scores ----
    float asv[2], adv[2];
    #pragma unroll
    for (int j = 0; j < 2; ++j) {
        int f = hf * 256 + w * 32 + j * 16 + rl;
        asv[j] = a_s[f]; adv[j] = a_d[f];
    }
    u16* Hg = HT + (size_t)g * 65536;
    #pragma unroll
    for (int i = 0; i < 8; ++i) {
        #pragma unroll
        for (int j = 0; j < 2; ++j) {
            int f = hf * 256 + w * 32 + j * 16 + rl;
            int node0 = i * 16 + grp * 4;
            ushort4 o;
            o.x = f2bf(acc[i][j][0]); o.y = f2bf(acc[i][j][1]);
            o.z = f2bf(acc[i][j][2]); o.w = f2bf(acc[i][j][3]);
            *(ushort4*)&Hg[(size_t)f * 128 + node0] = o;
        }
        #pragma unroll
        for (int r = 0; r < 4; ++r) {
            float s = acc[i][0][r] * asv[0] + acc[i][1][r] * asv[1];
            float d = acc[i][0][r] * adv[0] + acc[i][1][r] * adv[1];
            #pragma unroll
            for (int off = 1; off < 16; off <<= 1) {
                s += __shfl_xor(s, off);
                d += __shfl_xor(d, off);
            }
            if (rl == 0) {
                int node = i * 16 + grp * 4 + r;
                atomicAdd(&sA[node], s);
                atomicAdd(&dA[node], d);
            }
        }
    }
    __syncthreads();
    if (tid < 128) {
        atomicAdd(&SS[g * 128 + tid], sA[tid]);
        atomicAdd(&SD[g * 128 + tid], dA[tid]);
    }
}

// ---------------- kernel B: alpha + AGG, one block per graph ----------------
// LDS: Hts 128KB (H^T, source-pre-swizzled), cnt u4[128][128] in u32[2048], stats f32[512].
// MODE 0: out = bf16 gelu(AGG + bias) -> outU ; MODE 1: out = f32 (AGG + bias)*mask -> outF
template<int MODE>
__global__ __launch_bounds__(512) void gat_agg(
    const u16* __restrict__ HT, const int* __restrict__ ei,
    const float* __restrict__ SS, const float* __restrict__ SD,
    const float* __restrict__ bias, const int* __restrict__ valid,
    u16* __restrict__ outU, float* __restrict__ outF)
{
    __shared__ u16 Hts[65536];
    __shared__ u32 cntw[2048];
    __shared__ float stf[512];

    const int tid  = threadIdx.x;
    const int lane = tid & 63;
    const int w    = tid >> 6;
    const int rl   = lane & 15;
    const int grp  = lane >> 4;
    const int g    = blockIdx.x;
    const int bb   = g >> 5, tt = g & 31;

    const int4* es = (const int4*)(ei + (size_t)g * 4096);
    int4 e0 = es[tid], e1 = es[512 + tid];

    // stage H^T: lds[f][blk] <- global[f][blk ^ (f&15)] (pre-swizzled source, linear dest)
    const u16* Hg = HT + (size_t)g * 65536;
    #pragma unroll
    for (int it = 0; it < 16; ++it) {
        int f = it * 32 + (tid >> 4);
        int blk = tid & 15;
        GLOAD16(Hg + (size_t)f * 128 + ((blk ^ (f & 15)) * 8), &Hts[it * 4096 + w * 512]);
    }

    for (int i = tid; i < 2048; i += 512) cntw[i] = 0u;
    if (tid < 128) {
        stf[tid]       = SS[g * 128 + tid];
        stf[128 + tid] = SD[g * 128 + tid];
    }
    __syncthreads();   // drains GLOADs (vmcnt 0) + zero/score writes

    // ---- edge-count scatter (u4 nibbles) ----
    atomicAdd(&cntw[e1.x * 16 + (e0.x >> 3)], 1u << ((e0.x & 7) * 4));
    atomicAdd(&cntw[e1.y * 16 + (e0.y >> 3)], 1u << ((e0.y & 7) * 4));
    atomicAdd(&cntw[e1.z * 16 + (e0.z >> 3)], 1u << ((e0.z & 7) * 4));
    atomicAdd(&cntw[e1.w * 16 + (e0.w >> 3)], 1u << ((e0.w & 7) * 4));
    if (tid < 128) atomicAdd(&cntw[tid * 16 + (tid >> 3)], 1u << ((tid & 7) * 4));
    __syncthreads();

    // ---- softmax stats M, 1/D per dst row ----
    for (int r = 0; r < 16; ++r) {
        int m = w * 16 + r;
        float sdm = stf[128 + m];
        u32 w0 = cntw[m * 16 + (lane >> 3)];
        u32 w1 = cntw[m * 16 + 8 + (lane >> 3)];
        u32 c0 = (w0 >> ((lane & 7) * 4)) & 15u;
        u32 c1 = (w1 >> ((lane & 7) * 4)) & 15u;
        float E0 = stf[lane] + sdm;      E0 = E0 > 0.f ? E0 : 0.2f * E0;
        float E1 = stf[lane + 64] + sdm; E1 = E1 > 0.f ? E1 : 0.2f * E1;
        float mx = fmaxf(c0 ? E0 : -1e30f, c1 ? E1 : -1e30f);
        #pragma unroll
        for (int off = 1; off < 64; off <<= 1) mx = fmaxf(mx, __shfl_xor(mx, off));
        float p = (c0 ? (float)c0 * __expf(E0 - mx) : 0.f)
                + (c1 ? (float)c1 * __expf(E1 - mx) : 0.f);
        #pragma unroll
        for (int off = 1; off < 64; off <<= 1) p += __shfl_xor(p, off);
        if (lane == 0) { stf[256 + m] = mx; stf[384 + m] = 1.f / p; }
    }
    __syncthreads();

    // ---- alpha fragments (per-lane) ----
    const int m = w * 16 + rl;
    const float sdm = stf[128 + m], Mm = stf[256 + m], rDm = stf[384 + m];
    bf16x8 pa[4];
    #pragma unroll
    for (int kb = 0; kb < 4; ++kb) {
        u32 word = cntw[m * 16 + kb * 4 + grp];
        #pragma unroll
        for (int e = 0; e < 8; ++e) {
            u32 c = (word >> (e * 4)) & 15u;
            int s = kb * 32 + grp * 8 + e;
            float ev = stf[s] + sdm; ev = ev > 0.f ? ev : 0.2f * ev;
            float p = c ? (float)c * __expf(ev - Mm) * rDm : 0.f;
            pa[kb][e] = (__bf16)p;
        }
    }

    // ---- AGG in 8 chunks of 64 f ----
    const float msk = (MODE == 1) ? ((tt < valid[bb]) ? 1.f : 0.f) : 1.f;
    #pragma unroll 1
    for (int jc = 0; jc < 8; ++jc) {
        f32x4 acc2[4] = {};
        #pragma unroll
        for (int j4 = 0; j4 < 4; ++j4) {
            int f = jc * 64 + j4 * 16 + rl;
            #pragma unroll
            for (int kb = 0; kb < 4; ++kb) {
                bf16x8 hb = *(const bf16x8*)&Hts[f * 128 + (((kb * 4 + grp) ^ (f & 15)) * 8)];
                acc2[j4] = __builtin_amdgcn_mfma_f32_16x16x32_bf16(pa[kb], hb, acc2[j4], 0, 0, 0);
            }
        }
        #pragma unroll
        for (int j4 = 0; j4 < 4; ++j4) {
            int f = jc * 64 + j4 * 16 + rl;
            float bv = bias[f];
            #pragma unroll
            for (int r = 0; r < 4; ++r) {
                int m2 = w * 16 + grp * 4 + r;
                if (MODE == 0)
                    outU[(size_t)g * 65536 + m2 * 512 + f] = f2bf(gelu_f(acc2[j4][r] + bv));
                else
                    outF[(size_t)g * 65536 + m2 * 512 + f] = (acc2[j4][r] + bv) * msk;
            }
        }
    }
}

// ---------------- time mix: out = gelu(W_time @ y + b_time) + y, in-place ----------------
__global__ __launch_bounds__(256) void timemix_kernel(float* __restrict__ y,
                                                      const float* __restrict__ Wt,
                                                      const float* __restrict__ bt) {
    __shared__ float wsm[1024];
    __shared__ float bts[32];
    int tid = threadIdx.x;
    for (int i = tid; i < 1024; i += 256) wsm[i] = Wt[i];
    if (tid < 32) bts[tid] = bt[tid];
    __syncthreads();
    int blk = blockIdx.x;               // 2048 blocks
    int b = blk >> 8;
    int rem = blk & 255;
    int n = rem >> 1;
    int f = (rem & 1) * 256 + tid;
    size_t base = ((size_t)b * 4096 + n) * 512 + f;
    float ys[32];
    #pragma unroll
    for (int s = 0; s < 32; ++s) ys[s] = y[base + (size_t)s * 65536];
    #pragma unroll
    for (int t = 0; t < 32; ++t) {
        float a = bts[t];
        #pragma unroll
        for (int s = 0; s < 32; ++s) a += wsm[t * 32 + s] * ys[s];
        y[base + (size_t)t * 65536] = gelu_f(a) + ys[t];
    }
}

extern "C" void kernel_launch(void* const* d_in, const int* in_sizes, int n_in,
                              void* d_out, int out_size, void* d_ws, size_t ws_size,
                              hipStream_t stream) {
    const float* x     = (const float*)d_in[0];
    const int*   ei    = (const int*)d_in[1];
    const int*   valid = (const int*)d_in[2];
    const float* W1    = (const float*)d_in[3];
    const float* a1s   = (const float*)d_in[4];
    const float* a1d   = (const float*)d_in[5];
    const float* b1    = (const float*)d_in[6];
    const float* W2    = (const float*)d_in[7];
    const float* a2s   = (const float*)d_in[8];
    const float* a2d   = (const float*)d_in[9];
    const float* b2    = (const float*)d_in[10];
    const float* Wt    = (const float*)d_in[11];
    const float* bt    = (const float*)d_in[12];
    float* out = (float*)d_out;

    char* ws = (char*)d_ws;
    u16* Xb    = (u16*)(ws);                      // 33,554,432 B (x bf16; reused for H1')
    u16* HTb   = (u16*)(ws + 33554432);           // 33,554,432 B (H^T per layer)
    float* SS1 = (float*)(ws + 67108864);         // 131,072 B (zeroed by prep)
    float* SD1 = (float*)(ws + 67239936);
    float* SS2 = (float*)(ws + 67371008);
    float* SD2 = (float*)(ws + 67502080);

    prep_kernel<<<2048, 256, 0, stream>>>(x, Xb, SS1);

    // ---- layer 1 ----
    gat_gemm<<<512, 512, 0, stream>>>(Xb, W1, a1s, a1d, HTb, SS1, SD1);
    gat_agg<0><<<256, 512, 0, stream>>>(HTb, ei, SS1, SD1, b1, nullptr, Xb, nullptr);

    // ---- layer 2 ----
    gat_gemm<<<512, 512, 0, stream>>>(Xb, W2, a2s, a2d, HTb, SS2, SD2);
    gat_agg<1><<<256, 512, 0, stream>>>(HTb, ei, SS2, SD2, b2, valid, nullptr, out);

    // ---- time mixing (in-place on d_out) ----
    timemix_kernel<<<2048, 256, 0, stream>>>(out, Wt, bt);
}

// Round 12
// 194.821 us; speedup vs baseline: 1.5568x; 1.1304x over previous
//
#include <hip/hip_runtime.h>

using u16 = unsigned short;
using u32 = unsigned int;

typedef __bf16 bf16x8 __attribute__((ext_vector_type(8)));
typedef float  f32x4  __attribute__((ext_vector_type(4)));

__device__ __forceinline__ u16 f2bf(float f) {
    u32 u = __float_as_uint(f);
    u32 r = u + 0x7fffu + ((u >> 16) & 1u);
    return (u16)(r >> 16);
}
__device__ __forceinline__ float gelu_f(float x) {
    return 0.5f * x * (1.0f + erff(x * 0.70710678118654752440f));
}

#define GLOAD16(gp, lp) __builtin_amdgcn_global_load_lds( \
    (const __attribute__((address_space(1))) void*)(gp),  \
    (__attribute__((address_space(3))) void*)(lp), 16, 0, 0)

// ---------------- prep: cvt x/W1/W2 -> bf16, zero score buffers ----------------
__global__ __launch_bounds__(256) void prep_kernel(
    const float* __restrict__ x, const float* __restrict__ W1, const float* __restrict__ W2,
    u16* __restrict__ Xb, u16* __restrict__ W1b, u16* __restrict__ W2b,
    float* __restrict__ Z)
{
    const int i0 = blockIdx.x * 256 + threadIdx.x;
    const int stride = gridDim.x * 256;
    if (i0 < 32768) ((float4*)Z)[i0] = make_float4(0.f, 0.f, 0.f, 0.f);
    for (int i = i0; i < 65536; i += stride) {
        float4 v = ((const float4*)W1)[i];
        ushort4 o; o.x = f2bf(v.x); o.y = f2bf(v.y); o.z = f2bf(v.z); o.w = f2bf(v.w);
        ((ushort4*)W1b)[i] = o;
    }
    for (int i = i0; i < 65536; i += stride) {
        float4 v = ((const float4*)W2)[i];
        ushort4 o; o.x = f2bf(v.x); o.y = f2bf(v.y); o.z = f2bf(v.z); o.w = f2bf(v.w);
        ((ushort4*)W2b)[i] = o;
    }
    for (int i = i0; i < 4194304; i += stride) {
        float4 v = ((const float4*)x)[i];
        ushort4 o; o.x = f2bf(v.x); o.y = f2bf(v.y); o.z = f2bf(v.z); o.w = f2bf(v.w);
        ((ushort4*)Xb)[i] = o;
    }
}

// ---------------- kernel A: m97-clone GEMM + H^T + fused scores ----------------
// Block = (graph g, f-tile tn): 4 waves, 128m x 128f tile, BK=32 single-buffered.
// A = Xb[g] (bf16 [128][512]), B = Wb rows tn..tn+127 (bf16 [512][512]).
__global__ __launch_bounds__(256) void gat_gemm(
    const u16* __restrict__ A, const u16* __restrict__ Wb,
    const float* __restrict__ a_s, const float* __restrict__ a_d,
    u16* __restrict__ HT, float* __restrict__ SS, float* __restrict__ SD)
{
    __shared__ __align__(16) u16 As[128 * 32];
    __shared__ __align__(16) u16 Bs[128 * 32];
    __shared__ float sA[128], dA[128];

    const int tid  = threadIdx.x;
    const int lane = tid & 63;
    const int w    = tid >> 6;       // wave 0..3
    const int wm   = w & 1, wn = w >> 1;
    const int fr   = lane & 15;
    const int grp  = lane >> 4;
    const int ko   = grp * 8;
    const int g    = blockIdx.x >> 2;
    const int tn   = (blockIdx.x & 3) * 128;

    if (tid < 128) { sA[tid] = 0.f; dA[tid] = 0.f; }

    const int srow = lane >> 2;
    const int skel = (lane & 3) * 8;
    const u16* Ag0 = A  + (size_t)g * 65536 + (size_t)(w * 32 + srow) * 512 + skel;
    const u16* Bg0 = Wb + (size_t)(tn + w * 32 + srow) * 512 + skel;
    u16* Asl = &As[w * 1024];
    u16* Bsl = &Bs[w * 1024];

    f32x4 acc[4][4] = {};

    for (int kt = 0; kt < 16; ++kt) {
        GLOAD16(Ag0 + kt * 32,            Asl);
        GLOAD16(Ag0 + 16 * 512 + kt * 32, Asl + 512);
        GLOAD16(Bg0 + kt * 32,            Bsl);
        GLOAD16(Bg0 + 16 * 512 + kt * 32, Bsl + 512);
        __syncthreads();
        bf16x8 af[4], bf[4];
        #pragma unroll
        for (int i = 0; i < 4; ++i) {
            af[i] = *(const bf16x8*)&As[(wm * 64 + i * 16 + fr) * 32 + ko];
            bf[i] = *(const bf16x8*)&Bs[(wn * 64 + i * 16 + fr) * 32 + ko];
        }
        #pragma unroll
        for (int i = 0; i < 4; ++i)
            #pragma unroll
            for (int j = 0; j < 4; ++j)
                acc[i][j] = __builtin_amdgcn_mfma_f32_16x16x32_bf16(af[i], bf[j], acc[i][j], 0, 0, 0);
        __syncthreads();
    }

    // ---- epilogue: H^T write + fused scores ----
    float asv[4], adv[4];
    #pragma unroll
    for (int j = 0; j < 4; ++j) {
        int f = tn + wn * 64 + j * 16 + fr;
        asv[j] = a_s[f]; adv[j] = a_d[f];
    }
    u16* Hg = HT + (size_t)g * 65536;
    #pragma unroll
    for (int i = 0; i < 4; ++i) {
        int node0 = wm * 64 + i * 16 + grp * 4;
        #pragma unroll
        for (int j = 0; j < 4; ++j) {
            int f = tn + wn * 64 + j * 16 + fr;
            ushort4 o;
            o.x = f2bf(acc[i][j][0]); o.y = f2bf(acc[i][j][1]);
            o.z = f2bf(acc[i][j][2]); o.w = f2bf(acc[i][j][3]);
            *(ushort4*)&Hg[(size_t)f * 128 + node0] = o;
        }
        #pragma unroll
        for (int r = 0; r < 4; ++r) {
            float s = acc[i][0][r] * asv[0] + acc[i][1][r] * asv[1]
                    + acc[i][2][r] * asv[2] + acc[i][3][r] * asv[3];
            float d = acc[i][0][r] * adv[0] + acc[i][1][r] * adv[1]
                    + acc[i][2][r] * adv[2] + acc[i][3][r] * adv[3];
            #pragma unroll
            for (int off = 1; off < 16; off <<= 1) {
                s += __shfl_xor(s, off);
                d += __shfl_xor(d, off);
            }
            if (fr == 0) {
                atomicAdd(&sA[node0 + r], s);
                atomicAdd(&dA[node0 + r], d);
            }
        }
    }
    __syncthreads();
    if (tid < 128) {
        atomicAdd(&SS[g * 128 + tid], sA[tid]);
        atomicAdd(&SD[g * 128 + tid], dA[tid]);
    }
}

// ---------------- kernel B: alpha + AGG, one block per graph ----------------
// LDS: Hts 128KB (H^T, source-pre-swizzled), cnt u4[128][128] in u32[2048], stats f32[512].
// MODE 0: out = bf16 gelu(AGG + bias) -> outU ; MODE 1: out = f32 (AGG + bias)*mask -> outF
template<int MODE>
__global__ __launch_bounds__(512) void gat_agg(
    const u16* __restrict__ HT, const int* __restrict__ ei,
    const float* __restrict__ SS, const float* __restrict__ SD,
    const float* __restrict__ bias, const int* __restrict__ valid,
    u16* __restrict__ outU, float* __restrict__ outF)
{
    __shared__ u16 Hts[65536];
    __shared__ u32 cntw[2048];
    __shared__ float stf[512];

    const int tid  = threadIdx.x;
    const int lane = tid & 63;
    const int w    = tid >> 6;
    const int rl   = lane & 15;
    const int grp  = lane >> 4;
    const int g    = blockIdx.x;
    const int bb   = g >> 5, tt = g & 31;

    const int4* es = (const int4*)(ei + (size_t)g * 4096);
    int4 e0 = es[tid], e1 = es[512 + tid];

    // stage H^T: lds[f][blk] <- global[f][blk ^ (f&15)] (pre-swizzled source, linear dest)
    const u16* Hg = HT + (size_t)g * 65536;
    #pragma unroll
    for (int it = 0; it < 16; ++it) {
        int f = it * 32 + (tid >> 4);
        int blk = tid & 15;
        GLOAD16(Hg + (size_t)f * 128 + ((blk ^ (f & 15)) * 8), &Hts[it * 4096 + w * 512]);
    }

    for (int i = tid; i < 2048; i += 512) cntw[i] = 0u;
    if (tid < 128) {
        stf[tid]       = SS[g * 128 + tid];
        stf[128 + tid] = SD[g * 128 + tid];
    }
    __syncthreads();   // drains GLOADs + zero/score writes

    // ---- edge-count scatter (u4 nibbles) ----
    atomicAdd(&cntw[e1.x * 16 + (e0.x >> 3)], 1u << ((e0.x & 7) * 4));
    atomicAdd(&cntw[e1.y * 16 + (e0.y >> 3)], 1u << ((e0.y & 7) * 4));
    atomicAdd(&cntw[e1.z * 16 + (e0.z >> 3)], 1u << ((e0.z & 7) * 4));
    atomicAdd(&cntw[e1.w * 16 + (e0.w >> 3)], 1u << ((e0.w & 7) * 4));
    if (tid < 128) atomicAdd(&cntw[tid * 16 + (tid >> 3)], 1u << ((tid & 7) * 4));
    __syncthreads();

    // ---- softmax stats M, 1/D per dst row ----
    for (int r = 0; r < 16; ++r) {
        int m = w * 16 + r;
        float sdm = stf[128 + m];
        u32 w0 = cntw[m * 16 + (lane >> 3)];
        u32 w1 = cntw[m * 16 + 8 + (lane >> 3)];
        u32 c0 = (w0 >> ((lane & 7) * 4)) & 15u;
        u32 c1 = (w1 >> ((lane & 7) * 4)) & 15u;
        float E0 = stf[lane] + sdm;      E0 = E0 > 0.f ? E0 : 0.2f * E0;
        float E1 = stf[lane + 64] + sdm; E1 = E1 > 0.f ? E1 : 0.2f * E1;
        float mx = fmaxf(c0 ? E0 : -1e30f, c1 ? E1 : -1e30f);
        #pragma unroll
        for (int off = 1; off < 64; off <<= 1) mx = fmaxf(mx, __shfl_xor(mx, off));
        float p = (c0 ? (float)c0 * __expf(E0 - mx) : 0.f)
                + (c1 ? (float)c1 * __expf(E1 - mx) : 0.f);
        #pragma unroll
        for (int off = 1; off < 64; off <<= 1) p += __shfl_xor(p, off);
        if (lane == 0) { stf[256 + m] = mx; stf[384 + m] = 1.f / p; }
    }
    __syncthreads();

    // ---- alpha fragments (per-lane) ----
    const int m = w * 16 + rl;
    const float sdm = stf[128 + m], Mm = stf[256 + m], rDm = stf[384 + m];
    bf16x8 pa[4];
    #pragma unroll
    for (int kb = 0; kb < 4; ++kb) {
        u32 word = cntw[m * 16 + kb * 4 + grp];
        #pragma unroll
        for (int e = 0; e < 8; ++e) {
            u32 c = (word >> (e * 4)) & 15u;
            int s = kb * 32 + grp * 8 + e;
            float ev = stf[s] + sdm; ev = ev > 0.f ? ev : 0.2f * ev;
            float p = c ? (float)c * __expf(ev - Mm) * rDm : 0.f;
            pa[kb][e] = (__bf16)p;
        }
    }

    // ---- AGG in 8 chunks of 64 f ----
    const float msk = (MODE == 1) ? ((tt < valid[bb]) ? 1.f : 0.f) : 1.f;
    #pragma unroll 1
    for (int jc = 0; jc < 8; ++jc) {
        f32x4 acc2[4] = {};
        #pragma unroll
        for (int j4 = 0; j4 < 4; ++j4) {
            int f = jc * 64 + j4 * 16 + rl;
            #pragma unroll
            for (int kb = 0; kb < 4; ++kb) {
                bf16x8 hb = *(const bf16x8*)&Hts[f * 128 + (((kb * 4 + grp) ^ (f & 15)) * 8)];
                acc2[j4] = __builtin_amdgcn_mfma_f32_16x16x32_bf16(pa[kb], hb, acc2[j4], 0, 0, 0);
            }
        }
        #pragma unroll
        for (int j4 = 0; j4 < 4; ++j4) {
            int f = jc * 64 + j4 * 16 + rl;
            float bv = bias[f];
            #pragma unroll
            for (int r = 0; r < 4; ++r) {
                int m2 = w * 16 + grp * 4 + r;
                if (MODE == 0)
                    outU[(size_t)g * 65536 + m2 * 512 + f] = f2bf(gelu_f(acc2[j4][r] + bv));
                else
                    outF[(size_t)g * 65536 + m2 * 512 + f] = (acc2[j4][r] + bv) * msk;
            }
        }
    }
}

// ---------------- time mix: out = gelu(W_time @ y + b_time) + y, in-place ----------------
__global__ __launch_bounds__(256) void timemix_kernel(float* __restrict__ y,
                                                      const float* __restrict__ Wt,
                                                      const float* __restrict__ bt) {
    __shared__ float wsm[1024];
    __shared__ float bts[32];
    int tid = threadIdx.x;
    for (int i = tid; i < 1024; i += 256) wsm[i] = Wt[i];
    if (tid < 32) bts[tid] = bt[tid];
    __syncthreads();
    int blk = blockIdx.x;               // 2048 blocks
    int b = blk >> 8;
    int rem = blk & 255;
    int n = rem >> 1;
    int f = (rem & 1) * 256 + tid;
    size_t base = ((size_t)b * 4096 + n) * 512 + f;
    float ys[32];
    #pragma unroll
    for (int s = 0; s < 32; ++s) ys[s] = y[base + (size_t)s * 65536];
    #pragma unroll
    for (int t = 0; t < 32; ++t) {
        float a = bts[t];
        #pragma unroll
        for (int s = 0; s < 32; ++s) a += wsm[t * 32 + s] * ys[s];
        y[base + (size_t)t * 65536] = gelu_f(a) + ys[t];
    }
}

extern "C" void kernel_launch(void* const* d_in, const int* in_sizes, int n_in,
                              void* d_out, int out_size, void* d_ws, size_t ws_size,
                              hipStream_t stream) {
    const float* x     = (const float*)d_in[0];
    const int*   ei    = (const int*)d_in[1];
    const int*   valid = (const int*)d_in[2];
    const float* W1    = (const float*)d_in[3];
    const float* a1s   = (const float*)d_in[4];
    const float* a1d   = (const float*)d_in[5];
    const float* b1    = (const float*)d_in[6];
    const float* W2    = (const float*)d_in[7];
    const float* a2s   = (const float*)d_in[8];
    const float* a2d   = (const float*)d_in[9];
    const float* b2    = (const float*)d_in[10];
    const float* Wt    = (const float*)d_in[11];
    const float* bt    = (const float*)d_in[12];
    float* out = (float*)d_out;

    char* ws = (char*)d_ws;
    u16* Xb    = (u16*)(ws);                      // 33,554,432 B (x bf16; reused for H1')
    u16* HTb   = (u16*)(ws + 33554432);           // 33,554,432 B (H^T per layer)
    u16* W1b   = (u16*)(ws + 67108864);           //    524,288 B
    u16* W2b   = (u16*)(ws + 67633152);           //    524,288 B
    float* SS1 = (float*)(ws + 68157440);         //    131,072 B (zeroed by prep)
    float* SD1 = (float*)(ws + 68288512);
    float* SS2 = (float*)(ws + 68419584);
    float* SD2 = (float*)(ws + 68550656);

    prep_kernel<<<2048, 256, 0, stream>>>(x, W1, W2, Xb, W1b, W2b, SS1);

    // ---- layer 1 ----
    gat_gemm<<<1024, 256, 0, stream>>>(Xb, W1b, a1s, a1d, HTb, SS1, SD1);
    gat_agg<0><<<256, 512, 0, stream>>>(HTb, ei, SS1, SD1, b1, nullptr, Xb, nullptr);

    // ---- layer 2 ----
    gat_gemm<<<1024, 256, 0, stream>>>(Xb, W2b, a2s, a2d, HTb, SS2, SD2);
    gat_agg<1><<<256, 512, 0, stream>>>(HTb, ei, SS2, SD2, b2, valid, nullptr, out);

    // ---- time mixing (in-place on d_out) ----
    timemix_kernel<<<2048, 256, 0, stream>>>(out, Wt, bt);
}